// Round 4
// baseline (7859.867 us; speedup 1.0000x reference)
//
#include <hip/hip_runtime.h>

typedef _Float16 f16;
typedef _Float16 f16x8 __attribute__((ext_vector_type(8)));
typedef float f32x4 __attribute__((ext_vector_type(4)));
typedef unsigned int u32;
typedef unsigned long long u64;

#define TT 512
#define BB 512
#define DD 256
#define HH 512

// ws layout (bytes)
#define WPACK_BYTES (32*4*24*64*8*2)          // 3,145,728
#define HBUF_OFF    (WPACK_BYTES)
#define HBUF_BYTES  (2*BB*(HH/2)*8)           // tagged u64 pairs, 2 parities = 2 MB
#define HQ_PAR      (BB*(HH/2))               // u64s per parity = 131072

__device__ __forceinline__ float sigf(float v) {
    return __frcp_rn(1.0f + __expf(-v));
}
__device__ __forceinline__ float tanh_fast(float v) {
    float e = __expf(2.0f * fminf(v, 15.0f));
    return 1.0f - 2.0f * __frcp_rn(e + 1.0f);
}

// Pre-pack W = [W_ih | W_hh] (f32) into per-block, per-fragment f16 layout:
// Wp[ji][nt][ks][lane][8]  with gate row g = nt*512 + ji*16 + (lane&15),
// k = ks*32 + (lane>>4)*8 + j  (k<256 -> W_ih, else W_hh).
__global__ void pack_w(const float* __restrict__ W_ih,
                       const float* __restrict__ W_hh,
                       f16* __restrict__ Wp) {
    int tid = blockIdx.x * 256 + threadIdx.x;   // 32*4*24*64 = 196608 total
    if (tid >= 32*4*24*64) return;
    int lane = tid & 63;
    int rest = tid >> 6;
    int ks   = rest % 24;
    int t3   = rest / 24;
    int nt   = t3 & 3;
    int ji   = t3 >> 2;
    int g  = nt*512 + ji*16 + (lane & 15);
    int k0 = ks*32 + ((lane >> 4) & 3)*8;
    const float* src = (k0 < 256) ? (W_ih + (size_t)g*DD + k0)
                                  : (W_hh + (size_t)g*HH + (k0 - 256));
    f16x8 v;
    #pragma unroll
    for (int j = 0; j < 8; ++j) v[j] = (f16)src[j];
    *(f16x8*)(Wp + (size_t)tid*8) = v;
}

#define HLOAD(dstArr, sc_) do {                                                \
    _Pragma("unroll")                                                          \
    for (int c_ = 0; c_ < 4; ++c_)                                             \
        _Pragma("unroll")                                                      \
        for (int i_ = 0; i_ < 4; ++i_)                                         \
            dstArr[c_*4+i_] = __hip_atomic_load(hb + ((sc_)*4 + c_)*16 + i_,   \
                __ATOMIC_RELAXED, __HIP_MEMORY_SCOPE_AGENT);                   \
} while (0)

#define HSPIN(arr, sc_) do {                                                   \
    for (;;) {                                                                 \
        bool ok_ = true;                                                       \
        _Pragma("unroll")                                                      \
        for (int i_ = 0; i_ < 16; ++i_)                                        \
            ok_ = ok_ && ((u32)(arr[i_] >> 32) == want);                       \
        if (__all(ok_)) break;                                                 \
        HLOAD(arr, sc_);                                                       \
    }                                                                          \
} while (0)

#define HMFMA(arr, sc_) do {                                                   \
    _Pragma("unroll")                                                          \
    for (int c_ = 0; c_ < 4; ++c_) {                                           \
        union { u32 u[4]; f16x8 v; } F_;                                       \
        _Pragma("unroll")                                                      \
        for (int i_ = 0; i_ < 4; ++i_) F_.u[i_] = (u32)arr[c_*4+i_];           \
        _Pragma("unroll")                                                      \
        for (int nt_ = 0; nt_ < 4; ++nt_)                                      \
            acc[nt_] = __builtin_amdgcn_mfma_f32_16x16x32_f16(                 \
                Wlds[(nt_*24 + 8 + (sc_)*4 + c_)*64 + lane], F_.v,             \
                acc[nt_], 0, 0, 0);                                            \
    }                                                                          \
} while (0)

// Persistent LSTM kernel: 256 blocks x 256 threads. block = (bi = blk&7, ji = blk>>3).
// MFMA roles: A = W (m = 16 gate rows of gate-type nt), B = [x;h] (n = 16 batches).
// Handshake: h stored as tagged u64 = (step_tag << 32) | 2xf16 — the tag rides
// atomically with the data, so consumers spin directly on h. No flags, no
// producer-side vmcnt/release chain. Tags zeroed per launch (memset) ->
// deterministic. MFMA order fixed -> bitwise-stable accumulation.
__launch_bounds__(256, 1)
__global__ void lstm_fused(const float* __restrict__ x,
                           const float* __restrict__ b_ih,
                           const float* __restrict__ b_hh,
                           const float* __restrict__ W_fc,
                           const float* __restrict__ b_fc,
                           const f16* __restrict__ Wp,
                           u64* __restrict__ hq,
                           float* __restrict__ out) {
    extern __shared__ char smem[];
    f16x8* Wlds = (f16x8*)smem;          // [4][24][64] fragments, 96 KB

    const int tid  = threadIdx.x;
    const int lane = tid & 63;
    const int w    = tid >> 6;           // batch n-tile within group
    const int bi   = blockIdx.x & 7;
    const int ji   = blockIdx.x >> 3;

    {
        const f16x8* src = (const f16x8*)Wp + (size_t)ji * (4*24*64);
        for (int i = tid; i < 4*24*64; i += 256) Wlds[i] = src[i];
    }

    const int uq = (lane >> 4) * 4;      // unit quad within ji's 16 units
    float bias[4][4];
    #pragma unroll
    for (int nt = 0; nt < 4; ++nt)
        #pragma unroll
        for (int r = 0; r < 4; ++r)
            bias[nt][r] = b_ih[nt*512 + ji*16 + uq + r] + b_hh[nt*512 + ji*16 + uq + r];
    __syncthreads();                     // Wlds ready

    const int batch  = bi*64 + w*16 + (lane & 15);
    const float* xrow = x + (size_t)batch * TT * DD + ((lane >> 4) * 8);
    // consumer base: pairs of (batch, k-units (lane>>4)*8 ..+7) -> 4 u64/chunk
    const u64* hbase = hq + (size_t)batch * (HH/2) + (lane >> 4) * 4;
    // producer base: pairs of (batch, units ji*16+uq ..+3) -> 2 u64
    u64* hdst = hq + (size_t)batch * (HH/2) + ji*8 + (uq >> 1);

    float c[4] = {0.f, 0.f, 0.f, 0.f};
    f32x4 acc[4];

    // ---- prologue: acc = bias + x(0) * W_ih ----
    {
        float4 xa[8], xb[8];
        #pragma unroll
        for (int ks = 0; ks < 8; ++ks) {
            xa[ks] = *(const float4*)(xrow + ks*32);
            xb[ks] = *(const float4*)(xrow + ks*32 + 4);
        }
        #pragma unroll
        for (int nt = 0; nt < 4; ++nt)
            acc[nt] = (f32x4){bias[nt][0], bias[nt][1], bias[nt][2], bias[nt][3]};
        #pragma unroll
        for (int ks = 0; ks < 8; ++ks) {
            f16x8 a;
            a[0]=(f16)xa[ks].x; a[1]=(f16)xa[ks].y; a[2]=(f16)xa[ks].z; a[3]=(f16)xa[ks].w;
            a[4]=(f16)xb[ks].x; a[5]=(f16)xb[ks].y; a[6]=(f16)xb[ks].z; a[7]=(f16)xb[ks].w;
            #pragma unroll
            for (int nt = 0; nt < 4; ++nt)
                acc[nt] = __builtin_amdgcn_mfma_f32_16x16x32_f16(
                    Wlds[(nt*24 + ks)*64 + lane], a, acc[nt], 0, 0, 0);
        }
    }

    for (int s = 0; s < TT; ++s) {
        const u32 want = (u32)s;
        const u64* hb = hbase + (size_t)(s & 1) * HQ_PAR;
        u64 Areg[16], Breg[16];

        // ---- 1. issue h sc0, x(s+1), h sc1 (h first: sc0 check waits
        //         vmcnt(32), doesn't drain x on the fast path) ----
        if (s > 0) HLOAD(Areg, 0);
        float4 na[8], nb[8];
        const bool havex = (s + 1 < TT);
        if (havex) {
            const float* xs = xrow + (size_t)(s + 1) * DD;
            #pragma unroll
            for (int ks = 0; ks < 8; ++ks) {
                na[ks] = *(const float4*)(xs + ks*32);
                nb[ks] = *(const float4*)(xs + ks*32 + 4);
            }
        }

        // ---- 2. recurrent part: pipelined spin + MFMA over 4 super-chunks ----
        if (s > 0) {
            HLOAD(Breg, 1);
            HSPIN(Areg, 0); HMFMA(Areg, 0); HLOAD(Areg, 2);
            HSPIN(Breg, 1); HMFMA(Breg, 1); HLOAD(Breg, 3);
            HSPIN(Areg, 2); HMFMA(Areg, 2);
            HSPIN(Breg, 3); HMFMA(Breg, 3);
        }

        // ---- 3. cell: lane = (batch, units uq..uq+3) for all 4 gates ----
        union { f16 h[2]; u32 u; } P0, P1;
        {
            float ig, fg, gg, og;
            ig = sigf(acc[0][0]); fg = sigf(acc[1][0]);
            gg = tanh_fast(acc[2][0]); og = sigf(acc[3][0]);
            c[0] = fg * c[0] + ig * gg; P0.h[0] = (f16)(og * tanh_fast(c[0]));
            ig = sigf(acc[0][1]); fg = sigf(acc[1][1]);
            gg = tanh_fast(acc[2][1]); og = sigf(acc[3][1]);
            c[1] = fg * c[1] + ig * gg; P0.h[1] = (f16)(og * tanh_fast(c[1]));
            ig = sigf(acc[0][2]); fg = sigf(acc[1][2]);
            gg = tanh_fast(acc[2][2]); og = sigf(acc[3][2]);
            c[2] = fg * c[2] + ig * gg; P1.h[0] = (f16)(og * tanh_fast(c[2]));
            ig = sigf(acc[0][3]); fg = sigf(acc[1][3]);
            gg = tanh_fast(acc[2][3]); og = sigf(acc[3][3]);
            c[3] = fg * c[3] + ig * gg; P1.h[1] = (f16)(og * tanh_fast(c[3]));
        }
        {
            u64 tagq = ((u64)(u32)(s + 1)) << 32;
            u64* hd = hdst + (size_t)((s + 1) & 1) * HQ_PAR;
            __hip_atomic_store(hd,     tagq | P0.u, __ATOMIC_RELAXED,
                               __HIP_MEMORY_SCOPE_AGENT);
            __hip_atomic_store(hd + 1, tagq | P1.u, __ATOMIC_RELAXED,
                               __HIP_MEMORY_SCOPE_AGENT);
        }

        // ---- 4. tail: rebuild acc = bias + x(s+1)*W_ih ----
        if (havex) {
            #pragma unroll
            for (int nt = 0; nt < 4; ++nt)
                acc[nt] = (f32x4){bias[nt][0], bias[nt][1], bias[nt][2], bias[nt][3]};
            #pragma unroll
            for (int ks = 0; ks < 8; ++ks) {
                f16x8 a;
                a[0]=(f16)na[ks].x; a[1]=(f16)na[ks].y; a[2]=(f16)na[ks].z; a[3]=(f16)na[ks].w;
                a[4]=(f16)nb[ks].x; a[5]=(f16)nb[ks].y; a[6]=(f16)nb[ks].z; a[7]=(f16)nb[ks].w;
                #pragma unroll
                for (int nt = 0; nt < 4; ++nt)
                    acc[nt] = __builtin_amdgcn_mfma_f32_16x16x32_f16(
                        Wlds[(nt*24 + ks)*64 + lane], a, acc[nt], 0, 0, 0);
            }
        }
    }

    // ---- classifier head: blocks with ji == 0, one per batch group ----
    if (ji == 0) {
        const u32 wantT = (u32)TT;
        const u64* hT = hq + (size_t)(TT & 1) * HQ_PAR;
        float* red = (float*)smem;       // W no longer needed by this block's MFMA
        __syncthreads();                 // all waves past Wlds use
        int b_local = tid >> 2, seg = tid & 3;
        const u64* hr = hT + (size_t)(bi*64 + b_local) * (HH/2) + seg*64;
        const float* wf = W_fc + seg*128;
        float ssum = 0.f;
        #pragma unroll 1
        for (int g = 0; g < 8; ++g) {
            u64 gb[8];
            for (;;) {
                bool ok = true;
                #pragma unroll
                for (int i = 0; i < 8; ++i) {
                    gb[i] = __hip_atomic_load(hr + g*8 + i, __ATOMIC_RELAXED,
                                              __HIP_MEMORY_SCOPE_AGENT);
                    ok = ok && ((u32)(gb[i] >> 32) == wantT);
                }
                if (__all(ok)) break;
            }
            #pragma unroll
            for (int i = 0; i < 8; ++i) {
                union { f16 h[2]; u32 u; } Pv;
                Pv.u = (u32)gb[i];
                ssum += (float)Pv.h[0] * wf[g*16 + 2*i]
                      + (float)Pv.h[1] * wf[g*16 + 2*i + 1];
            }
        }
        red[b_local*4 + seg] = ssum;
        __syncthreads();
        if (tid < 64) {
            float v = red[tid*4+0] + red[tid*4+1] + red[tid*4+2] + red[tid*4+3] + b_fc[0];
            out[bi*64 + tid] = sigf(v);
        }
    }
}

extern "C" void kernel_launch(void* const* d_in, const int* in_sizes, int n_in,
                              void* d_out, int out_size, void* d_ws, size_t ws_size,
                              hipStream_t stream) {
    const float* x    = (const float*)d_in[0];
    const float* W_ih = (const float*)d_in[1];
    const float* W_hh = (const float*)d_in[2];
    const float* b_ih = (const float*)d_in[3];
    const float* b_hh = (const float*)d_in[4];
    const float* W_fc = (const float*)d_in[5];
    const float* b_fc = (const float*)d_in[6];
    float* out = (float*)d_out;

    f16* Wp = (f16*)d_ws;
    u64* hq = (u64*)((char*)d_ws + HBUF_OFF);

    hipMemsetAsync(hq, 0, HBUF_BYTES, stream);   // zero tags: no stale matches
    pack_w<<<768, 256, 0, stream>>>(W_ih, W_hh, Wp);

    static bool attr_set = []() {
        hipFuncSetAttribute(reinterpret_cast<const void*>(lstm_fused),
                            hipFuncAttributeMaxDynamicSharedMemorySize, 98304);
        return true;
    }();
    (void)attr_set;

    void* kargs[] = {(void*)&x, (void*)&b_ih, (void*)&b_hh, (void*)&W_fc,
                     (void*)&b_fc, (void*)&Wp, (void*)&hq, (void*)&out};
    hipLaunchCooperativeKernel(reinterpret_cast<const void*>(lstm_fused),
                               dim3(256), dim3(256), kargs, 98304, stream);
}

// Round 5
// 3295.604 us; speedup vs baseline: 2.3850x; 2.3850x over previous
//
#include <hip/hip_runtime.h>

typedef _Float16 f16;
typedef _Float16 f16x8 __attribute__((ext_vector_type(8)));
typedef float f32x4 __attribute__((ext_vector_type(4)));
typedef unsigned int u32;
typedef unsigned long long u64;

#define TT 512
#define BB 512
#define DD 256
#define HH 512

// ws layout (bytes)
#define WPACK_BYTES (32*4*24*64*8*2)          // 3,145,728
#define HBUF_OFF    (WPACK_BYTES)             // 2 * 512*512 f16 = 1,048,576
#define FLAG_OFF    (HBUF_OFF + 2*BB*HH*2)
#define NFLAGS      ((TT+1)*8*4*32)           // 525,312 u32

__device__ __forceinline__ float sigf(float v) {
    return __frcp_rn(1.0f + __expf(-v));
}
__device__ __forceinline__ float tanh_fast(float v) {
    float e = __expf(2.0f * fminf(v, 15.0f));
    return 1.0f - 2.0f * __frcp_rn(e + 1.0f);
}

// Pre-pack W = [W_ih | W_hh] (f32) into per-block, per-fragment f16 layout:
// Wp[ji][nt][ks][lane][8]  with gate row g = nt*512 + ji*16 + (lane&15),
// k = ks*32 + (lane>>4)*8 + j  (k<256 -> W_ih, else W_hh).
__global__ void pack_w(const float* __restrict__ W_ih,
                       const float* __restrict__ W_hh,
                       f16* __restrict__ Wp) {
    int tid = blockIdx.x * 256 + threadIdx.x;   // 32*4*24*64 = 196608 total
    if (tid >= 32*4*24*64) return;
    int lane = tid & 63;
    int rest = tid >> 6;
    int ks   = rest % 24;
    int t3   = rest / 24;
    int nt   = t3 & 3;
    int ji   = t3 >> 2;
    int g  = nt*512 + ji*16 + (lane & 15);
    int k0 = ks*32 + ((lane >> 4) & 3)*8;
    const float* src = (k0 < 256) ? (W_ih + (size_t)g*DD + k0)
                                  : (W_hh + (size_t)g*HH + (k0 - 256));
    f16x8 v;
    #pragma unroll
    for (int j = 0; j < 8; ++j) v[j] = (f16)src[j];
    *(f16x8*)(Wp + (size_t)tid*8) = v;
}

// Persistent LSTM kernel: 256 blocks x 256 threads. block = (bi = blk&7, ji = blk>>3).
// MFMA roles: A = W (m = 16 gate rows of gate-type nt), B = [x;h] (n = 16 batches).
// R3 flag protocol; R5 schedule: per step
//   poll (clean VMEM queue) -> h loads -> rec MFMA -> cell -> h store ->
//   vmcnt(0) -> flag store -> x(s+1) loads + x-MFMA tail.
// Tail sits between release and next poll: hides peer production + drains the
// flag-store ack, so the poll's first read never waits on our own HBM traffic.
__launch_bounds__(256, 1)
__global__ void lstm_fused(const float* __restrict__ x,
                           const float* __restrict__ b_ih,
                           const float* __restrict__ b_hh,
                           const float* __restrict__ W_fc,
                           const float* __restrict__ b_fc,
                           const f16* __restrict__ Wp,
                           f16* __restrict__ hbuf,
                           u32* __restrict__ flags,
                           float* __restrict__ out) {
    extern __shared__ char smem[];
    f16x8* Wlds = (f16x8*)smem;          // [4][24][64] fragments, 96 KB

    const int tid  = threadIdx.x;
    const int lane = tid & 63;
    const int w    = tid >> 6;           // batch n-tile within group
    const int bi   = blockIdx.x & 7;
    const int ji   = blockIdx.x >> 3;

    {
        const f16x8* src = (const f16x8*)Wp + (size_t)ji * (4*24*64);
        for (int i = tid; i < 4*24*64; i += 256) Wlds[i] = src[i];
    }

    const int uq = (lane >> 4) * 4;      // unit quad within ji's 16 units
    float bias[4][4];
    #pragma unroll
    for (int nt = 0; nt < 4; ++nt)
        #pragma unroll
        for (int r = 0; r < 4; ++r)
            bias[nt][r] = b_ih[nt*512 + ji*16 + uq + r] + b_hh[nt*512 + ji*16 + uq + r];
    __syncthreads();                     // Wlds ready

    const int batch  = bi*64 + w*16 + (lane & 15);
    const int koff   = (lane >> 4) * 8;
    const float* xrow = x + (size_t)batch * TT * DD + koff;
    u64* hq = (u64*)hbuf;
    const int hrow_q = (batch * HH + koff) >> 2;                // u64 index
    u64* hdst0 = hq + ((batch * HH + ji*16 + uq) >> 2);

    float c[4] = {0.f, 0.f, 0.f, 0.f};
    f32x4 acc[4];

    // ---- prologue: acc = bias + x(0) * W_ih ----
    {
        float4 xa[8], xb[8];
        #pragma unroll
        for (int ks = 0; ks < 8; ++ks) {
            xa[ks] = *(const float4*)(xrow + ks*32);
            xb[ks] = *(const float4*)(xrow + ks*32 + 4);
        }
        #pragma unroll
        for (int nt = 0; nt < 4; ++nt)
            acc[nt] = (f32x4){bias[nt][0], bias[nt][1], bias[nt][2], bias[nt][3]};
        #pragma unroll
        for (int ks = 0; ks < 8; ++ks) {
            f16x8 a;
            a[0]=(f16)xa[ks].x; a[1]=(f16)xa[ks].y; a[2]=(f16)xa[ks].z; a[3]=(f16)xa[ks].w;
            a[4]=(f16)xb[ks].x; a[5]=(f16)xb[ks].y; a[6]=(f16)xb[ks].z; a[7]=(f16)xb[ks].w;
            #pragma unroll
            for (int nt = 0; nt < 4; ++nt)
                acc[nt] = __builtin_amdgcn_mfma_f32_16x16x32_f16(
                    Wlds[(nt*24 + ks)*64 + lane], a, acc[nt], 0, 0, 0);
        }
    }

    for (int s = 0; s < TT; ++s) {
        // ---- 1. recurrent part: poll (clean queue), h loads, 64 MFMA ----
        if (s > 0) {
            const u32* f = flags + (((size_t)s*8 + bi)*4 + w)*32;
            for (;;) {
                u32 v = 1u;
                if (lane < 32)
                    v = __hip_atomic_load(&f[lane], __ATOMIC_RELAXED,
                                          __HIP_MEMORY_SCOPE_AGENT);
                if (__all(v != 0)) break;
                __builtin_amdgcn_s_sleep(1);
            }
            asm volatile("" ::: "memory");   // no h-load hoist above poll

            const size_t pbase = (size_t)(s & 1) * (BB*HH/4);
            union HU { u64 q[2]; f16x8 v; };
            HU A[16];
            #pragma unroll
            for (int ks = 0; ks < 16; ++ks) {
                size_t qi = pbase + hrow_q + (size_t)ks * 8;
                A[ks].q[0] = __hip_atomic_load(hq + qi,     __ATOMIC_RELAXED,
                                               __HIP_MEMORY_SCOPE_AGENT);
                A[ks].q[1] = __hip_atomic_load(hq + qi + 1, __ATOMIC_RELAXED,
                                               __HIP_MEMORY_SCOPE_AGENT);
            }
            #pragma unroll
            for (int ks = 0; ks < 16; ++ks)
                #pragma unroll
                for (int nt = 0; nt < 4; ++nt)
                    acc[nt] = __builtin_amdgcn_mfma_f32_16x16x32_f16(
                        Wlds[(nt*24 + ks + 8)*64 + lane], A[ks].v, acc[nt], 0, 0, 0);
        }

        // ---- 2. cell: lane = (batch, units uq..uq+3) for all 4 gates ----
        union { u64 q; f16 h4[4]; } H;
        #pragma unroll
        for (int r = 0; r < 4; ++r) {
            float ig = sigf(acc[0][r]);
            float fg = sigf(acc[1][r]);
            float gg = tanh_fast(acc[2][r]);
            float og = sigf(acc[3][r]);
            c[r] = fg * c[r] + ig * gg;
            H.h4[r] = (f16)(og * tanh_fast(c[r]));
        }
        __hip_atomic_store(hdst0 + (size_t)((s + 1) & 1) * (BB*HH/4), H.q,
                           __ATOMIC_RELAXED, __HIP_MEMORY_SCOPE_AGENT);

        // ---- 3. release ASAP: only the h store is outstanding here ----
        asm volatile("s_waitcnt vmcnt(0)" ::: "memory");
        if (lane == 0)
            __hip_atomic_store(&flags[(((size_t)(s + 1)*8 + bi)*4 + w)*32 + ji],
                               1u, __ATOMIC_RELAXED, __HIP_MEMORY_SCOPE_AGENT);

        // ---- 4. tail (off critical path): x(s+1) load + x-MFMA; also drains
        //         the flag-store ack before the next poll ----
        if (s + 1 < TT) {
            const float* xs = xrow + (size_t)(s + 1) * DD;
            float4 na[8], nb[8];
            #pragma unroll
            for (int ks = 0; ks < 8; ++ks) {
                na[ks] = *(const float4*)(xs + ks*32);
                nb[ks] = *(const float4*)(xs + ks*32 + 4);
            }
            #pragma unroll
            for (int nt = 0; nt < 4; ++nt)
                acc[nt] = (f32x4){bias[nt][0], bias[nt][1], bias[nt][2], bias[nt][3]};
            #pragma unroll
            for (int ks = 0; ks < 8; ++ks) {
                f16x8 a;
                a[0]=(f16)na[ks].x; a[1]=(f16)na[ks].y; a[2]=(f16)na[ks].z; a[3]=(f16)na[ks].w;
                a[4]=(f16)nb[ks].x; a[5]=(f16)nb[ks].y; a[6]=(f16)nb[ks].z; a[7]=(f16)nb[ks].w;
                #pragma unroll
                for (int nt = 0; nt < 4; ++nt)
                    acc[nt] = __builtin_amdgcn_mfma_f32_16x16x32_f16(
                        Wlds[(nt*24 + ks)*64 + lane], a, acc[nt], 0, 0, 0);
            }
        }
    }

    // ---- classifier head: blocks with ji == 0, one per batch group ----
    if (ji == 0) {
        {
            const u32* f = flags + (((size_t)TT*8 + bi)*4 + w)*32;
            for (;;) {
                u32 v = 1u;
                if (lane < 32)
                    v = __hip_atomic_load(&f[lane], __ATOMIC_RELAXED,
                                          __HIP_MEMORY_SCOPE_AGENT);
                if (__all(v != 0)) break;
                __builtin_amdgcn_s_sleep(1);
            }
        }
        asm volatile("" ::: "memory");
        __syncthreads();   // all 4 waves' domains ready -> all 64 batches ready
        const u64* hT = hq + (size_t)(TT & 1) * (BB*HH/4);
        float* red = (float*)smem;       // W no longer needed
        int b_local = tid >> 2, seg = tid & 3;
        const u64* hr = hT + (((size_t)(bi*64 + b_local) * HH + seg*128) >> 2);
        const float* wf = W_fc + seg*128;
        float ssum = 0.f;
        for (int kq = 0; kq < 32; ++kq) {
            union { u64 q; f16 h4[4]; } Hv;
            Hv.q = __hip_atomic_load(hr + kq, __ATOMIC_RELAXED,
                                     __HIP_MEMORY_SCOPE_AGENT);
            #pragma unroll
            for (int j = 0; j < 4; ++j) ssum += (float)Hv.h4[j] * wf[kq*4 + j];
        }
        red[b_local*4 + seg] = ssum;
        __syncthreads();
        if (tid < 64) {
            float v = red[tid*4+0] + red[tid*4+1] + red[tid*4+2] + red[tid*4+3] + b_fc[0];
            out[bi*64 + tid] = sigf(v);
        }
    }
}

extern "C" void kernel_launch(void* const* d_in, const int* in_sizes, int n_in,
                              void* d_out, int out_size, void* d_ws, size_t ws_size,
                              hipStream_t stream) {
    const float* x    = (const float*)d_in[0];
    const float* W_ih = (const float*)d_in[1];
    const float* W_hh = (const float*)d_in[2];
    const float* b_ih = (const float*)d_in[3];
    const float* b_hh = (const float*)d_in[4];
    const float* W_fc = (const float*)d_in[5];
    const float* b_fc = (const float*)d_in[6];
    float* out = (float*)d_out;

    f16* Wp    = (f16*)d_ws;
    f16* hbuf  = (f16*)((char*)d_ws + HBUF_OFF);
    u32* flags = (u32*)((char*)d_ws + FLAG_OFF);

    hipMemsetAsync(flags, 0, NFLAGS * sizeof(u32), stream);
    pack_w<<<768, 256, 0, stream>>>(W_ih, W_hh, Wp);

    static bool attr_set = []() {
        hipFuncSetAttribute(reinterpret_cast<const void*>(lstm_fused),
                            hipFuncAttributeMaxDynamicSharedMemorySize, 98304);
        return true;
    }();
    (void)attr_set;

    void* kargs[] = {(void*)&x, (void*)&b_ih, (void*)&b_hh, (void*)&W_fc,
                     (void*)&b_fc, (void*)&Wp, (void*)&hbuf, (void*)&flags,
                     (void*)&out};
    hipLaunchCooperativeKernel(reinterpret_cast<const void*>(lstm_fused),
                               dim3(256), dim3(256), kargs, 98304, stream);
}